// Round 7
// baseline (360.065 us; speedup 1.0000x reference)
//
#include <hip/hip_runtime.h>
#include <hip/hip_bf16.h>

typedef __bf16 bf16x8 __attribute__((ext_vector_type(8)));
typedef float floatx4 __attribute__((ext_vector_type(4)));
typedef unsigned short ushort_t;

// ---- 8-element fp32 load -> bf16x8 ----
__device__ __forceinline__ bf16x8 load8f(const float* p) {
  const float4* q = reinterpret_cast<const float4*>(p);
  float4 x = q[0], y = q[1];
  bf16x8 r;
  r[0] = (__bf16)x.x; r[1] = (__bf16)x.y; r[2] = (__bf16)x.z; r[3] = (__bf16)x.w;
  r[4] = (__bf16)y.x; r[5] = (__bf16)y.y; r[6] = (__bf16)y.z; r[7] = (__bf16)y.w;
  return r;
}
__device__ __forceinline__ bf16x8 pack8(float4 x, float4 y) {
  bf16x8 r;
  r[0] = (__bf16)x.x; r[1] = (__bf16)x.y; r[2] = (__bf16)x.z; r[3] = (__bf16)x.w;
  r[4] = (__bf16)y.x; r[5] = (__bf16)y.y; r[6] = (__bf16)y.z; r[7] = (__bf16)y.w;
  return r;
}

// ---- epilogue stores ----
__device__ __forceinline__ void storeC(float* C, long idx, float v) { C[idx] = v; }
__device__ __forceinline__ void storeC(ushort_t* C, long idx, float v) {
  __bf16 b = (__bf16)v;
  C[idx] = __builtin_bit_cast(ushort_t, b);
}

// async global->LDS, 16B per lane (LDS dest linear: wave base + lane*16)
__device__ __forceinline__ void glds16(const ushort_t* g, ushort_t* l) {
  __builtin_amdgcn_global_load_lds(
      (const __attribute__((address_space(1))) void*)g,
      (__attribute__((address_space(3))) void*)l, 16, 0, 0);
}

__device__ __forceinline__ void bar_raw()  { asm volatile("s_barrier" ::: "memory"); }
__device__ __forceinline__ void wait_vm0() { asm volatile("s_waitcnt vmcnt(0)" ::: "memory"); }
// counted waits + scheduling fence (rule 18: pin dependent ops below)
__device__ __forceinline__ void wv4s() {
  asm volatile("s_waitcnt vmcnt(4)" ::: "memory");
  __builtin_amdgcn_sched_barrier(0);
}
__device__ __forceinline__ void wv0s() {
  asm volatile("s_waitcnt vmcnt(0)" ::: "memory");
  __builtin_amdgcn_sched_barrier(0);
}
__device__ __forceinline__ void wlg12() {
  asm volatile("s_waitcnt lgkmcnt(12)" ::: "memory");
  __builtin_amdgcn_sched_barrier(0);
}
__device__ __forceinline__ void wlg8() {
  asm volatile("s_waitcnt lgkmcnt(8)" ::: "memory");
  __builtin_amdgcn_sched_barrier(0);
}
__device__ __forceinline__ void wlg4() {
  asm volatile("s_waitcnt lgkmcnt(4)" ::: "memory");
  __builtin_amdgcn_sched_barrier(0);
}
__device__ __forceinline__ void wlg0() {
  asm volatile("s_waitcnt lgkmcnt(0)" ::: "memory");
  __builtin_amdgcn_sched_barrier(0);
}

// =====================================================================
// fp32 -> bf16 convert (weights only) + mask j0 scan.
// =====================================================================
__global__ __launch_bounds__(256) void cvt3m(
    const float* __restrict__ Wq, const float* __restrict__ Wk,
    const float* __restrict__ Wv, ushort_t* __restrict__ dstW, long nw,
    const int* __restrict__ mask, int* __restrict__ j0, int S, int B)
{
  const int z = blockIdx.y;
  const float* s = (z == 0) ? Wq : ((z == 1) ? Wk : Wv);
  ushort_t* d = dstW + (long)z * nw;
  const long i = (((long)blockIdx.x * 256) + threadIdx.x) * 8;
  if (i < nw) {
    bf16x8 v = load8f(s + i);
    *reinterpret_cast<bf16x8*>(d + i) = v;
  }
  if (z == 0 && (int)blockIdx.x < B) {
    const int b = blockIdx.x;
    const int* m = mask + (long)b * S;
    const int tid = threadIdx.x;
    int best = S;
    for (int j = tid; j < S; j += 256)
      if (m[j] != 0) best = min(best, j);
    #pragma unroll
    for (int off = 32; off; off >>= 1)
      best = min(best, __shfl_xor(best, off));
    __shared__ int red[4];
    if ((tid & 63) == 0) red[tid >> 6] = best;
    __syncthreads();
    if (tid == 0) j0[b] = min(min(red[0], red[1]), min(red[2], red[3]));
  }
}

// =====================================================================
// 256x256 bf16 NT GEMM core (R5, benched; used by scores8/pv8).
// =====================================================================
template<typename TC>
__device__ __forceinline__ void gemm256_core(
    const ushort_t* __restrict__ Apan, const ushort_t* __restrict__ Bpan,
    const float* __restrict__ bias, int bias_mode,
    TC* __restrict__ C, int bm, int bn, int N, int K, int G, float alpha)
{
  __shared__ ushort_t Ab[2][2][128 * 64];
  __shared__ ushort_t Bb[2][2][128 * 64];

  const int tid = threadIdx.x;
  const int wv = tid >> 6;
  const int lane = tid & 63;
  const int wr = wv >> 2, wc = wv & 3;
  const int lr = lane & 15, lq = lane >> 4;

  const int q0 = tid << 4;
  const int r0 = q0 >> 7;
  const int c0 = ((q0 & 127) ^ ((r0 & 7) << 4)) >> 1;
  const int lo0 = q0 >> 1;
  const int lo1 = lo0 + 4096;
  const long Kl = K;

  const ushort_t* As0 = Apan + (long)r0 * Kl + c0;
  const ushort_t* Bs0 = Bpan + (long)r0 * Kl + c0;

  auto stA = [&](int t, int h) {
    const ushort_t* s = As0 + (long)(h * 128) * Kl + t * 64;
    ushort_t* d = &Ab[t & 1][h][0];
    glds16(s, d + lo0);
    glds16(s + 64 * Kl, d + lo1);
  };
  auto stB = [&](int t, int h) {
    const ushort_t* s = Bs0 + (long)(h * 128) * Kl + t * 64;
    ushort_t* d = &Bb[t & 1][h][0];
    glds16(s, d + lo0);
    glds16(s + 64 * Kl, d + lo1);
  };

  const int aco0 = ((lq * 16) ^ ((lr & 7) << 4)) >> 1;
  const int aco1 = ((64 + lq * 16) ^ ((lr & 7) << 4)) >> 1;

  floatx4 acc[8][4];
  #pragma unroll
  for (int i = 0; i < 8; ++i)
    #pragma unroll
    for (int j = 0; j < 4; ++j)
      acc[i][j] = (floatx4){0.f, 0.f, 0.f, 0.f};

  bf16x8 a0[4][2], a1[4][2], b0[2][2], b1[2][2];

  auto ldA4 = [&](bf16x8 (&a)[4][2], int buf, int i0) {
    const ushort_t* Ah = &Ab[buf][wr][lr * 64];
    #pragma unroll
    for (int i = 0; i < 4; ++i) {
      a[i][0] = *reinterpret_cast<const bf16x8*>(Ah + (i0 + i) * 1024 + aco0);
      a[i][1] = *reinterpret_cast<const bf16x8*>(Ah + (i0 + i) * 1024 + aco1);
    }
  };
  auto ldB2 = [&](bf16x8 (&b)[2][2], int buf, int j0) {
    const ushort_t* Bh = &Bb[buf][wc >> 1][(wc & 1) * 4096 + lr * 64];
    #pragma unroll
    for (int j = 0; j < 2; ++j) {
      b[j][0] = *reinterpret_cast<const bf16x8*>(Bh + (j0 + j) * 1024 + aco0);
      b[j][1] = *reinterpret_cast<const bf16x8*>(Bh + (j0 + j) * 1024 + aco1);
    }
  };
  auto MM = [&](int I0, bf16x8 (&AF)[4][2], int J0, bf16x8 (&BF)[2][2]) {
    #pragma unroll
    for (int i = 0; i < 4; ++i)
      #pragma unroll
      for (int j = 0; j < 2; ++j) {
        acc[I0 + i][J0 + j] = __builtin_amdgcn_mfma_f32_16x16x32_bf16(
            AF[i][0], BF[j][0], acc[I0 + i][J0 + j], 0, 0, 0);
        acc[I0 + i][J0 + j] = __builtin_amdgcn_mfma_f32_16x16x32_bf16(
            AF[i][1], BF[j][1], acc[I0 + i][J0 + j], 0, 0, 0);
      }
  };

  stA(0, 0); stA(0, 1); stB(0, 0); stB(0, 1);
  wait_vm0();
  bar_raw();

  for (int t = 0; t < G; ++t) {
    const int buf = t & 1;
    if (t + 1 < G) { stA(t + 1, 0); stA(t + 1, 1); stB(t + 1, 0); stB(t + 1, 1); }
    __builtin_amdgcn_sched_barrier(0);
    ldA4(a0, buf, 0);
    ldB2(b0, buf, 0);
    __builtin_amdgcn_sched_barrier(0);
    ldB2(b1, buf, 2);
    __builtin_amdgcn_sched_barrier(0);
    ldA4(a1, buf, 4);
    __builtin_amdgcn_sched_barrier(0);
    wlg12();
    __builtin_amdgcn_s_setprio(1);
    MM(0, a0, 0, b0);
    __builtin_amdgcn_s_setprio(0);
    wlg8();
    __builtin_amdgcn_s_setprio(1);
    MM(0, a0, 2, b1);
    __builtin_amdgcn_s_setprio(0);
    wlg0();
    __builtin_amdgcn_s_setprio(1);
    MM(4, a1, 0, b0);
    MM(4, a1, 2, b1);
    __builtin_amdgcn_s_setprio(0);
    wait_vm0();
    bar_raw();
  }

  #pragma unroll
  for (int i = 0; i < 8; ++i) {
    #pragma unroll
    for (int j = 0; j < 4; ++j) {
      const int row0 = bm * 256 + wr * 128 + i * 16 + lq * 4;
      const int col  = bn * 256 + wc * 64 + j * 16 + lr;
      #pragma unroll
      for (int r = 0; r < 4; ++r) {
        float v = acc[i][j][r] * alpha;
        if (bias_mode == 1) v += bias[col];
        else if (bias_mode == 2) v += bias[row0 + r];
        storeC(C, (long)(row0 + r) * N + col, v);
      }
    }
  }
}

// =====================================================================
// Fused-convert 256x256 GEMM core for projections (K=1024, G=16).
// LDS is passed in from the caller so the two template instantiations
// in projF share one 128 KB allocation (R6 fix). fp32 operand is
// reg-staged in two 16-float halves with disjoint live ranges:
//   ldF0 @ tile top        (covered by frag reads + clusters 1-2)
//   wrF0 + ldF1 @ mid      (vmcnt(4): ldF0 drained, stH in flight;
//                           fl0 dead before fl1 born -> regs reused)
//   wrF1 @ end behind vm0  (ldF1 covered by a1 reads + clusters 3-4)
// ds_write swizzle invariant == glds16 pre-swizzled-source invariant:
// LDS[row][c] = src[row][c ^ ((row&7)<<3 ushorts)] both paths.
// F32A=true: fp32 -> A tile (q/k). F32A=false: fp32 -> B tile (vT).
// =====================================================================
template<typename TC, bool F32A>
__device__ __forceinline__ void gemm256f(
    ushort_t* __restrict__ AbL, ushort_t* __restrict__ BbL,
    const float* __restrict__ Fsrc, const ushort_t* __restrict__ Hsrc,
    const float* __restrict__ bias, int bias_mode,
    TC* __restrict__ C, int bm, int bn, int N, float alpha)
{
  const int K = 1024, G = 16;

  const int tid = threadIdx.x;
  const int wv = tid >> 6;
  const int lane = tid & 63;
  const int wr = wv >> 2, wc = wv & 3;
  const int lr = lane & 15, lq = lane >> 4;

  auto AB = [&](int buf, int h) -> ushort_t* { return AbL + ((buf * 2 + h) << 13); };
  auto BB = [&](int buf, int h) -> ushort_t* { return BbL + ((buf * 2 + h) << 13); };

  // glds16 staging for the bf16 (weight) side
  const int q0 = tid << 4;
  const int r0 = q0 >> 7;
  const int c0 = ((q0 & 127) ^ ((r0 & 7) << 4)) >> 1;
  const int lo0 = q0 >> 1;
  const int lo1 = lo0 + 4096;
  const ushort_t* Hs0 = Hsrc + (long)r0 * K + c0;
  auto stH = [&](int t) {
    #pragma unroll
    for (int h = 0; h < 2; ++h) {
      const ushort_t* s = Hs0 + (long)(h * 128) * K + t * 64;
      ushort_t* d = F32A ? BB(t & 1, h) : AB(t & 1, h);
      glds16(s, d + lo0);
      glds16(s + 64 * K, d + lo1);
    }
  };

  // fp32 reg staging: thread covers row rr, 32 cols cc..cc+31, 2 halves
  const int rr = tid >> 1, cc = (tid & 1) << 5;
  const int rl = rr & 127, hh = rr >> 7;
  const int sw = (rl & 7) << 3;            // swizzle, ushort units
  const float* Fs0 = Fsrc + (long)rr * K + cc;
  float4 fl0[4], fl1[4];
  auto ldF0 = [&](int t) {
    const float4* p = reinterpret_cast<const float4*>(Fs0 + t * 64);
    #pragma unroll
    for (int i = 0; i < 4; ++i) fl0[i] = p[i];
  };
  auto ldF1 = [&](int t) {
    const float4* p = reinterpret_cast<const float4*>(Fs0 + t * 64 + 16);
    #pragma unroll
    for (int i = 0; i < 4; ++i) fl1[i] = p[i];
  };
  auto wrF0 = [&](int t) {
    ushort_t* dst = (F32A ? AB(t & 1, hh) : BB(t & 1, hh)) + rl * 64;
    *reinterpret_cast<bf16x8*>(dst + ((cc + 0) ^ sw)) = pack8(fl0[0], fl0[1]);
    *reinterpret_cast<bf16x8*>(dst + ((cc + 8) ^ sw)) = pack8(fl0[2], fl0[3]);
  };
  auto wrF1 = [&](int t) {
    ushort_t* dst = (F32A ? AB(t & 1, hh) : BB(t & 1, hh)) + rl * 64;
    *reinterpret_cast<bf16x8*>(dst + ((cc + 16) ^ sw)) = pack8(fl1[0], fl1[1]);
    *reinterpret_cast<bf16x8*>(dst + ((cc + 24) ^ sw)) = pack8(fl1[2], fl1[3]);
  };

  const int aco0 = ((lq * 16) ^ ((lr & 7) << 4)) >> 1;
  const int aco1 = ((64 + lq * 16) ^ ((lr & 7) << 4)) >> 1;

  floatx4 acc[8][4];
  #pragma unroll
  for (int i = 0; i < 8; ++i)
    #pragma unroll
    for (int j = 0; j < 4; ++j)
      acc[i][j] = (floatx4){0.f, 0.f, 0.f, 0.f};

  bf16x8 a0[4][2], a1[4][2], b0[2][2], b1[2][2];

  auto ldA4 = [&](bf16x8 (&a)[4][2], int buf, int i0) {
    const ushort_t* Ah = AB(buf, wr) + lr * 64;
    #pragma unroll
    for (int i = 0; i < 4; ++i) {
      a[i][0] = *reinterpret_cast<const bf16x8*>(Ah + (i0 + i) * 1024 + aco0);
      a[i][1] = *reinterpret_cast<const bf16x8*>(Ah + (i0 + i) * 1024 + aco1);
    }
  };
  auto ldB2 = [&](bf16x8 (&b)[2][2], int buf, int j0) {
    const ushort_t* Bh = BB(buf, wc >> 1) + (wc & 1) * 4096 + lr * 64;
    #pragma unroll
    for (int j = 0; j < 2; ++j) {
      b[j][0] = *reinterpret_cast<const bf16x8*>(Bh + (j0 + j) * 1024 + aco0);
      b[j][1] = *reinterpret_cast<const bf16x8*>(Bh + (j0 + j) * 1024 + aco1);
    }
  };
  auto MM = [&](int I0, bf16x8 (&AF)[4][2], int J0, bf16x8 (&BF)[2][2]) {
    #pragma unroll
    for (int i = 0; i < 4; ++i)
      #pragma unroll
      for (int j = 0; j < 2; ++j) {
        acc[I0 + i][J0 + j] = __builtin_amdgcn_mfma_f32_16x16x32_bf16(
            AF[i][0], BF[j][0], acc[I0 + i][J0 + j], 0, 0, 0);
        acc[I0 + i][J0 + j] = __builtin_amdgcn_mfma_f32_16x16x32_bf16(
            AF[i][1], BF[j][1], acc[I0 + i][J0 + j], 0, 0, 0);
      }
  };

  // prologue: tile 0 staged serially (once per block)
  ldF0(0); stH(0);                  // queue: ldF0(4), stH(4)
  wv4s();                           // ldF0 drained, stH in flight
  wrF0(0);
  ldF1(0);
  wv0s();                           // ldF1 + stH drained
  wrF1(0);
  wlg0();                           // ds_writes drained
  bar_raw();

  for (int t = 0; t < G; ++t) {
    const int buf = t & 1;
    const bool pre = (t + 1 < G);
    if (pre) {
      ldF0(t + 1);                  // 4 fp32 loads (oldest in vm queue)
      stH(t + 1);                   // 4 glds16 -> buf^1
    }
    __builtin_amdgcn_sched_barrier(0);
    ldA4(a0, buf, 0);
    ldB2(b0, buf, 0);
    __builtin_amdgcn_sched_barrier(0);
    ldB2(b1, buf, 2);               // 16 ds_reads outstanding
    __builtin_amdgcn_sched_barrier(0);
    wlg4();                         // a0,b0 ready; b1 in flight
    __builtin_amdgcn_s_setprio(1);
    MM(0, a0, 0, b0);
    __builtin_amdgcn_s_setprio(0);
    wlg0();                         // b1 ready
    __builtin_amdgcn_s_setprio(1);
    MM(0, a0, 2, b1);
    __builtin_amdgcn_s_setprio(0);
    if (pre) {
      wv4s();                       // ldF0 drained (stH still in flight)
      wrF0(t + 1);                  // cvt + swizzled ds_write, buf^1
      ldF1(t + 1);                  // fl0 dead -> regs reused for fl1
      __builtin_amdgcn_sched_barrier(0);
    }
    ldA4(a1, buf, 4);
    __builtin_amdgcn_sched_barrier(0);
    wlg0();                         // a1 ready (also drains wrF0 writes)
    __builtin_amdgcn_s_setprio(1);
    MM(4, a1, 0, b0);
    MM(4, a1, 2, b1);
    __builtin_amdgcn_s_setprio(0);
    if (pre) {
      wv0s();                       // ldF1 + stH drained
      wrF1(t + 1);
      wlg0();                       // ds_writes drained before barrier
    } else {
      wait_vm0();
    }
    bar_raw();
  }

  #pragma unroll
  for (int i = 0; i < 8; ++i) {
    #pragma unroll
    for (int j = 0; j < 4; ++j) {
      const int row0 = bm * 256 + wr * 128 + i * 16 + lq * 4;
      const int col  = bn * 256 + wc * 64 + j * 16 + lr;
      #pragma unroll
      for (int r = 0; r < 4; ++r) {
        float v = acc[i][j][r] * alpha;
        if (bias_mode == 1) v += bias[col];
        else if (bias_mode == 2) v += bias[row0 + r];
        storeC(C, (long)(row0 + r) * N + col, v);
      }
    }
  }
}

// =====================================================================
// Fused projections (cvt folded in): jobs 0-255 -> q/k from fp32 Q/K
// (A-side fp32, B-side bf16 weights); jobs 256-383 -> vT from fp32 V
// (B-side fp32, A-side bf16 Wv). XCD-chunked remap (384 = 8 x 48).
// Shared LDS hoisted here so both gemm256f instantiations use it.
// =====================================================================
__global__ __launch_bounds__(512) void projF(
    const float* __restrict__ Qf, const float* __restrict__ Kf,
    const float* __restrict__ Vf, const ushort_t* __restrict__ Wb,
    const float* __restrict__ bq, const float* __restrict__ bk,
    const float* __restrict__ bv,
    ushort_t* __restrict__ qk, ushort_t* __restrict__ vT,
    long NQ, long NW)
{
  __shared__ ushort_t AbS[2][2][128 * 64];   // 64 KB
  __shared__ ushort_t BbS[2][2][128 * 64];   // 64 KB
  ushort_t* AbL = &AbS[0][0][0];
  ushort_t* BbL = &BbS[0][0][0];

  const int h = blockIdx.x;
  const int s = (h & 7) * 48 + (h >> 3);           // XCD-chunked remap
  if (s < 256) {
    const int z = s >> 7, r = s & 127;
    const int bm = r >> 2, bn = r & 3;             // 32 x 4
    const float* F = (z ? Kf : Qf) + (long)bm * 256 * 1024;
    const ushort_t* H = Wb + (long)z * NW + (long)bn * 256 * 1024;
    gemm256f<ushort_t, true>(AbL, BbL, F, H, z ? bk : bq, 1,
                             qk + (long)z * NQ, bm, bn, 1024, 1.0f);
  } else {
    const int u = s - 256, vb = u >> 5, r = u & 31;
    const int bm = r >> 3, bn = r & 7;             // 4 x 8
    const float* F = Vf + (long)vb * (2048L * 1024) + (long)bn * 256 * 1024;
    const ushort_t* H = Wb + 2 * NW + (long)bm * 256 * 1024;
    gemm256f<ushort_t, false>(AbL, BbL, F, H, bv, 2,
                              vT + (long)vb * (1024L * 2048), bm, bn, 2048, 1.0f);
  }
}

// =====================================================================
// Scores: Sc_b = q_b . k_b^T / 32. Flat 256-slot grid, XCD-chunked,
// lower-triangle-first remap per batch, causal 256-tile skip via j0.
// =====================================================================
__global__ __launch_bounds__(512) void scores8(
    const ushort_t* __restrict__ qb, const ushort_t* __restrict__ kb,
    ushort_t* __restrict__ Sc, const int* __restrict__ j0p)
{
  const int h = blockIdx.x;
  const int job = (h & 7) * 32 + (h >> 3);         // XCD-chunked remap
  const int bz = job >> 6;
  const int s = job & 63;
  int bm, bn;
  if (s < 36) {
    int r = 0;
    while ((r + 1) * (r + 2) / 2 <= s) ++r;
    bm = r; bn = s - r * (r + 1) / 2;
  } else {
    int u = s - 36, r = 0;
    while (u >= 7 - r) { u -= 7 - r; ++r; }
    bm = r; bn = r + 1 + u;
  }
  if (bn > bm && j0p[bz] <= bm * 256) return;
  const long SD = 2048L * 1024;
  gemm256_core<ushort_t>(qb + (long)bz * SD + (long)bm * 256 * 1024,
                         kb + (long)bz * SD + (long)bn * 256 * 1024,
                         nullptr, 0, Sc + (long)bz * 2048 * 2048,
                         bm, bn, 2048, 1024, 16, 0.03125f);
}

// =====================================================================
// PV: O_b = P_b . vT_b^T with causal K-trim AND split-K makespan fix.
// =====================================================================
__global__ __launch_bounds__(512) void pv8(
    const ushort_t* __restrict__ P, const ushort_t* __restrict__ vT,
    float* __restrict__ out, float* __restrict__ scr,
    const int* __restrict__ j0p)
{
  const int h = blockIdx.x;
  const int job = (h & 7) * 32 + (h >> 3);         // XCD-chunked remap
  const int bz = job >> 6;
  const int r = job & 63;
  const int bm = r >> 3;
  const int kh = (r >> 2) & 1;
  const int bn = r & 3;

  const int Gf = (j0p[bz] <= bm * 256) ? (bm + 1) * 4 : 32;
  int g0, g1;
  if (Gf > 8) {
    const int half = Gf >> 1;
    g0 = kh ? half : 0;
    g1 = kh ? Gf : half;
  } else {
    if (kh) return;
    g0 = 0; g1 = Gf;
  }

  float* Cc = kh ? (scr + (long)bz * (2048L * 1024))
                 : (out + (long)bz * (2048L * 1024));
  gemm256_core<float>(
      P  + (long)bz * (2048L * 2048) + (long)bm * 256 * 2048 + g0 * 64,
      vT + (long)bz * (1024L * 2048) + (long)bn * 256 * 2048 + g0 * 64,
      nullptr, 0, Cc, bm, bn, 1024, 2048, g1 - g0, 1.0f);
}

// =====================================================================
// Split-K combine: out += scr for rows whose PV block split (Gf > 8).
// =====================================================================
__global__ __launch_bounds__(256) void pv_combine(
    float* __restrict__ out, const float* __restrict__ scr,
    const int* __restrict__ j0p)
{
  const long u = (((long)blockIdx.x * 256) + threadIdx.x) * 8;
  const int bz = (int)(u >> 21);
  const long rem = u & ((1L << 21) - 1);
  const int row = (int)(rem >> 10);
  const int bm = row >> 8;
  const int Gf = (j0p[bz] <= bm * 256) ? (bm + 1) * 4 : 32;
  if (Gf <= 8) return;
  float4* o = reinterpret_cast<float4*>(out + u);
  const float4* s = reinterpret_cast<const float4*>(scr + u);
  float4 o0 = o[0], o1 = o[1], s0 = s[0], s1 = s[1];
  o0.x += s0.x; o0.y += s0.y; o0.z += s0.z; o0.w += s0.w;
  o1.x += s1.x; o1.y += s1.y; o1.z += s1.z; o1.w += s1.w;
  o[0] = o0; o[1] = o1;
}

// =====================================================================
// Row softmax, exact reference ordering; bf16 Sc in, bf16 P out.
// Causal trim at 256 granularity, matched with pv8's K-trim.
// =====================================================================
__global__ __launch_bounds__(256) void softmax_causal(
    const ushort_t* __restrict__ Sc, ushort_t* __restrict__ P,
    const int* __restrict__ mask, const int* __restrict__ j0p, int S)
{
  const int i = blockIdx.x, b = blockIdx.y;
  const ushort_t* row = Sc + ((long)b * S + i) * S;
  ushort_t* prow = P + ((long)b * S + i) * S;
  const int* mrow = mask + (long)b * S;
  const int tid = threadIdx.x;
  const int lane = tid & 63, wave = tid >> 6;
  const int j0 = tid * 8;
  __shared__ float red[4];

  const int blk = i >> 8;
  const int jmax = (j0p[b] <= (blk << 8)) ? ((blk + 1) << 8) : S;
  const bool act = (j0 < jmax);

  float vals[8];
  float mymax = -3.4e38f;
  if (act) {
    bf16x8 sv = *reinterpret_cast<const bf16x8*>(row + j0);
    const int4* mp = reinterpret_cast<const int4*>(mrow + j0);
    int4 m0 = mp[0], m1 = mp[1];
    int mk[8] = {m0.x, m0.y, m0.z, m0.w, m1.x, m1.y, m1.z, m1.w};
    #pragma unroll
    for (int u = 0; u < 8; ++u) {
      const int j = j0 + u;
      float v = (float)sv[u];
      if (mk[u] == 0) v = -1e10f;
      if (j > i) v += -1e10f;
      vals[u] = v;
      mymax = fmaxf(mymax, v);
    }
  }
  #pragma unroll
  for (int off = 32; off; off >>= 1)
    mymax = fmaxf(mymax, __shfl_xor(mymax, off));
  if (lane == 0) red[wave] = mymax;
  __syncthreads();
  const float m = fmaxf(fmaxf(red[0], red[1]), fmaxf(red[2], red[3]));
  __syncthreads();

  float sum = 0.f;
  if (act) {
    #pragma unroll
    for (int u = 0; u < 8; ++u) {
      const float e = __expf(vals[u] - m);
      vals[u] = e;
      sum += e;
    }
  }
  #pragma unroll
  for (int off = 32; off; off >>= 1)
    sum += __shfl_xor(sum, off);
  if (lane == 0) red[wave] = sum;
  __syncthreads();
  const float tot = red[0] + red[1] + red[2] + red[3];
  const float inv = 1.0f / tot;

  if (act) {
    bf16x8 pv;
    #pragma unroll
    for (int u = 0; u < 8; ++u) pv[u] = (__bf16)(vals[u] * inv);
    *reinterpret_cast<bf16x8*>(prow + j0) = pv;
  }
}

extern "C" void kernel_launch(void* const* d_in, const int* in_sizes, int n_in,
                              void* d_out, int out_size, void* d_ws, size_t ws_size,
                              hipStream_t stream)
{
  const int B = 4, S = 2048, D = 1024;
  const float* Q  = (const float*)d_in[0];
  const float* K  = (const float*)d_in[1];
  const float* V  = (const float*)d_in[2];
  const int*   am = (const int*)d_in[3];
  const float* Wq = (const float*)d_in[4];
  const float* bq = (const float*)d_in[5];
  const float* Wk = (const float*)d_in[6];
  const float* bk = (const float*)d_in[7];
  const float* Wv = (const float*)d_in[8];
  const float* bv = (const float*)d_in[9];
  float* out = (float*)d_out;

  const long MS = (long)B * S;       // 8192
  const long NQ = MS * D;            // 8.39M elems = 16 MB bf16
  const long NW = (long)D * D;       // 1.05M elems = 2 MB bf16

  // ws layout; aliases ordering-safe on the sequential stream:
  //  Sc (bf16, 34MB) in the ScB region (3*NQ = 50MB)
  //  P  (bf16, 34MB) = qb..kb   (q,k dead after scores GEMM)
  //  scr(fp32, 34MB) = ScB      (Sc dead after softmax)
  ushort_t* qb = (ushort_t*)d_ws;
  ushort_t* kb = qb + NQ;
  ushort_t* vT = kb + NQ;
  ushort_t* ScB = vT + NQ;           // 3*NQ region for Sc / scr
  ushort_t* Wqb = ScB + 3 * NQ;
  int* j0 = (int*)(Wqb + 3 * NW);
  ushort_t* Sc = ScB;
  ushort_t* P  = qb;                 // alias
  float* scr   = (float*)ScB;        // alias (PV split-K partials)

  // weights convert + j0 scan (activation converts fused into projF)
  cvt3m<<<dim3((int)(NW / 2048), 3), dim3(256), 0, stream>>>(
      Wq, Wk, Wv, Wqb, NW, am, j0, S, B);

  // fused projections: q, k, vT straight from fp32 Q/K/V
  projF<<<dim3(384), dim3(512), 0, stream>>>(Q, K, V, Wqb, bq, bk, bv,
                                             qb, vT, NQ, NW);

  // Sc_b = q_b . k_b^T / 32, causal skip + lower-tri remap + XCD chunking
  scores8<<<dim3(256), dim3(512), 0, stream>>>(qb, kb, Sc, j0);

  // softmax (mask + causal, reference ordering, 256-granular trim)
  softmax_causal<<<dim3(S, B), dim3(256), 0, stream>>>(Sc, P, am, j0, S);

  // O_b = P_b . vT_b^T, causal K-trim + split-K (max 16 K-tiles/block)
  pv8<<<dim3(256), dim3(512), 0, stream>>>(P, vT, out, scr, j0);
  pv_combine<<<dim3((int)(MS * D / 8 / 256)), dim3(256), 0, stream>>>(out, scr, j0);
}

// Round 8
// 318.872 us; speedup vs baseline: 1.1292x; 1.1292x over previous
//
#include <hip/hip_runtime.h>
#include <hip/hip_bf16.h>

typedef __bf16 bf16x8 __attribute__((ext_vector_type(8)));
typedef float floatx4 __attribute__((ext_vector_type(4)));
typedef unsigned short ushort_t;

// ---- 8-element fp32 load -> bf16x8 ----
__device__ __forceinline__ bf16x8 load8f(const float* p) {
  const float4* q = reinterpret_cast<const float4*>(p);
  float4 x = q[0], y = q[1];
  bf16x8 r;
  r[0] = (__bf16)x.x; r[1] = (__bf16)x.y; r[2] = (__bf16)x.z; r[3] = (__bf16)x.w;
  r[4] = (__bf16)y.x; r[5] = (__bf16)y.y; r[6] = (__bf16)y.z; r[7] = (__bf16)y.w;
  return r;
}

// ---- epilogue stores ----
__device__ __forceinline__ void storeC(float* C, long idx, float v) { C[idx] = v; }
__device__ __forceinline__ void storeC(ushort_t* C, long idx, float v) {
  __bf16 b = (__bf16)v;
  C[idx] = __builtin_bit_cast(ushort_t, b);
}

// async global->LDS, 16B per lane (LDS dest linear: wave base + lane*16)
__device__ __forceinline__ void glds16(const ushort_t* g, ushort_t* l) {
  __builtin_amdgcn_global_load_lds(
      (const __attribute__((address_space(1))) void*)g,
      (__attribute__((address_space(3))) void*)l, 16, 0, 0);
}

__device__ __forceinline__ void bar_raw()  { asm volatile("s_barrier" ::: "memory"); }
__device__ __forceinline__ void lgkm0()    { asm volatile("s_waitcnt lgkmcnt(0)" ::: "memory"); }
__device__ __forceinline__ void wait_vm4() { asm volatile("s_waitcnt vmcnt(4)" ::: "memory"); }
__device__ __forceinline__ void wait_vm0() { asm volatile("s_waitcnt vmcnt(0)" ::: "memory"); }

// =====================================================================
// Merged fp32 -> bf16 convert for QKV (big) and W (small), 3 sources
// each via blockIdx.y. Folds the mask j0 scan into y==0, x<B blocks.
// (R4-verified)
// =====================================================================
__global__ __launch_bounds__(256) void cvt3m(
    const float* __restrict__ Q, const float* __restrict__ K,
    const float* __restrict__ V, const float* __restrict__ Wq,
    const float* __restrict__ Wk, const float* __restrict__ Wv,
    ushort_t* __restrict__ dstQ, ushort_t* __restrict__ dstW,
    long nq, long nw,
    const int* __restrict__ mask, int* __restrict__ j0, int S, int B)
{
  const int z = blockIdx.y;
  const long bq = nq >> 11;                  // blocks for the big convert
  long x = blockIdx.x;
  const float* s; ushort_t* d; long n;
  if (x < bq) {
    s = (z == 0) ? Q : ((z == 1) ? K : V);
    d = dstQ + (long)z * nq; n = nq;
  } else {
    x -= bq;
    s = (z == 0) ? Wq : ((z == 1) ? Wk : Wv);
    d = dstW + (long)z * nw; n = nw;
  }
  const long i = ((x * 256) + threadIdx.x) * 8;
  if (i < n) {
    bf16x8 v = load8f(s + i);
    *reinterpret_cast<bf16x8*>(d + i) = v;
  }
  if (z == 0 && (int)blockIdx.x < B) {
    const int b = blockIdx.x;
    const int* m = mask + (long)b * S;
    const int tid = threadIdx.x;
    int best = S;
    for (int j = tid; j < S; j += 256)
      if (m[j] != 0) best = min(best, j);
    #pragma unroll
    for (int off = 32; off; off >>= 1)
      best = min(best, __shfl_xor(best, off));
    __shared__ int red[4];
    if ((tid & 63) == 0) red[tid >> 6] = best;
    __syncthreads();
    if (tid == 0) j0[b] = min(min(red[0], red[1]), min(red[2], red[3]));
  }
}

// =====================================================================
// 256x256 8-phase bf16 NT GEMM core (R4-benched, best-known: 322.5us
// config). 8 waves (2Mx4N), wave tile 128x64, BK=64, LDS 128 KB
// double-buffered, XOR-swizzle (row&7)<<4 on pre-swizzled global source
// + ds_read addrs (0 bank conflicts, R3-measured). Counted vmcnt(4)
// once per K-tile (T4); stages A(t+1) in ph1/2, B(t+2) in ph3/4.
// =====================================================================
template<typename TC>
__device__ __forceinline__ void gemm256_core(
    const ushort_t* __restrict__ Apan,   // + bm*256*K (+ k-offset for split)
    const ushort_t* __restrict__ Bpan,   // + bn*256*K (+ k-offset for split)
    const float* __restrict__ bias, int bias_mode,
    TC* __restrict__ C, int bm, int bn, int N, int K, int G, float alpha)
{
  __shared__ ushort_t Ab[2][2][128 * 64];   // 64 KB
  __shared__ ushort_t Bb[2][2][128 * 64];   // 64 KB

  const int tid = threadIdx.x;            // 0..511
  const int wv = tid >> 6;
  const int lane = tid & 63;
  const int wr = wv >> 2, wc = wv & 3;    // 2 x 4 wave grid
  const int lr = lane & 15, lq = lane >> 4;

  // --- staging geometry (pre-swizzled global source, linear LDS dest) ---
  const int q0 = tid << 4;                            // byte in half-tile, line0
  const int r0 = q0 >> 7;                             // local row 0..63
  const int c0 = ((q0 & 127) ^ ((r0 & 7) << 4)) >> 1; // swizzled col (ushorts)
  const int lo0 = q0 >> 1;                            // LDS ushort offset line0
  const int lo1 = lo0 + 4096;                         // line1 (+8 KB)
  const long Kl = K;

  const ushort_t* As0 = Apan + (long)r0 * Kl + c0;
  const ushort_t* Bs0 = Bpan + (long)r0 * Kl + c0;

  auto stA = [&](int t, int h) {
    const ushort_t* s = As0 + (long)(h * 128) * Kl + t * 64;
    ushort_t* d = &Ab[t & 1][h][0];
    glds16(s, d + lo0);
    glds16(s + 64 * Kl, d + lo1);   // rows r0+64, same swizzled col
  };
  auto stB = [&](int t, int h) {
    const ushort_t* s = Bs0 + (long)(h * 128) * Kl + t * 64;
    ushort_t* d = &Bb[t & 1][h][0];
    glds16(s, d + lo0);
    glds16(s + 64 * Kl, d + lo1);
  };

  // --- frag read offsets (swizzled) ---
  const int aco0 = ((lq * 16) ^ ((lr & 7) << 4)) >> 1;        // ks=0
  const int aco1 = ((64 + lq * 16) ^ ((lr & 7) << 4)) >> 1;   // ks=1

  floatx4 acc[8][4];
  #pragma unroll
  for (int i = 0; i < 8; ++i)
    #pragma unroll
    for (int j = 0; j < 4; ++j)
      acc[i][j] = (floatx4){0.f, 0.f, 0.f, 0.f};

  bf16x8 a0[4][2], a1[4][2], b0[2][2], b1[2][2];

  auto ldA4 = [&](bf16x8 (&a)[4][2], int buf, int i0) {
    const ushort_t* Ah = &Ab[buf][wr][lr * 64];
    #pragma unroll
    for (int i = 0; i < 4; ++i) {
      a[i][0] = *reinterpret_cast<const bf16x8*>(Ah + (i0 + i) * 1024 + aco0);
      a[i][1] = *reinterpret_cast<const bf16x8*>(Ah + (i0 + i) * 1024 + aco1);
    }
  };
  auto ldB2 = [&](bf16x8 (&b)[2][2], int buf, int j0) {
    const ushort_t* Bh = &Bb[buf][wc >> 1][(wc & 1) * 4096 + lr * 64];
    #pragma unroll
    for (int j = 0; j < 2; ++j) {
      b[j][0] = *reinterpret_cast<const bf16x8*>(Bh + (j0 + j) * 1024 + aco0);
      b[j][1] = *reinterpret_cast<const bf16x8*>(Bh + (j0 + j) * 1024 + aco1);
    }
  };
  auto MM = [&](int I0, bf16x8 (&AF)[4][2], int J0, bf16x8 (&BF)[2][2]) {
    #pragma unroll
    for (int i = 0; i < 4; ++i)
      #pragma unroll
      for (int j = 0; j < 2; ++j) {
        acc[I0 + i][J0 + j] = __builtin_amdgcn_mfma_f32_16x16x32_bf16(
            AF[i][0], BF[j][0], acc[I0 + i][J0 + j], 0, 0, 0);
        acc[I0 + i][J0 + j] = __builtin_amdgcn_mfma_f32_16x16x32_bf16(
            AF[i][1], BF[j][1], acc[I0 + i][J0 + j], 0, 0, 0);
      }
  };

  // prologue: 12 loads; vmcnt(4) => B(0),A(0) resident, B(1) in flight
  stB(0, 0); stB(0, 1);
  stA(0, 0); stA(0, 1);
  stB(1, 0); stB(1, 1);
  wait_vm4();
  bar_raw();

  for (int t = 0; t < G; ++t) {
    const int buf = t & 1;
    // ---- phase 1: quad (rows 0-63, cols 0-31) ----
    ldA4(a0, buf, 0);
    ldB2(b0, buf, 0);
    if (t + 1 < G) stA(t + 1, 0);
    bar_raw(); lgkm0();
    __builtin_amdgcn_s_setprio(1);
    MM(0, a0, 0, b0);
    __builtin_amdgcn_s_setprio(0);
    bar_raw();
    // ---- phase 2: quad (rows 0-63, cols 32-63) ----
    ldB2(b1, buf, 2);
    if (t + 1 < G) stA(t + 1, 1);
    bar_raw(); lgkm0();
    __builtin_amdgcn_s_setprio(1);
    MM(0, a0, 2, b1);
    __builtin_amdgcn_s_setprio(0);
    bar_raw();
    // ---- phase 3: quad (rows 64-127, cols 0-31) ----
    ldA4(a1, buf, 4);
    if (t + 2 < G) stB(t + 2, 0);
    bar_raw(); lgkm0();
    __builtin_amdgcn_s_setprio(1);
    MM(4, a1, 0, b0);
    __builtin_amdgcn_s_setprio(0);
    bar_raw();
    // ---- phase 4: quad (rows 64-127, cols 32-63) ----
    if (t + 2 < G) { stB(t + 2, 1); wait_vm4(); }
    else if (t + 1 < G) wait_vm0();
    bar_raw(); lgkm0();
    __builtin_amdgcn_s_setprio(1);
    MM(4, a1, 2, b1);
    __builtin_amdgcn_s_setprio(0);
    bar_raw();
  }

  // epilogue: C/D layout col=lane&15, row=quad*4+reg (m89-verified)
  #pragma unroll
  for (int i = 0; i < 8; ++i) {
    #pragma unroll
    for (int j = 0; j < 4; ++j) {
      const int row0 = bm * 256 + wr * 128 + i * 16 + lq * 4;
      const int col  = bn * 256 + wc * 64 + j * 16 + lr;
      #pragma unroll
      for (int r = 0; r < 4; ++r) {
        float v = acc[i][j][r] * alpha;
        if (bias_mode == 1) v += bias[col];
        else if (bias_mode == 2) v += bias[row0 + r];
        storeC(C, (long)(row0 + r) * N + col, v);
      }
    }
  }
}

// =====================================================================
// projQK: q = Q.Wq^T+bq (z=0), k = K.Wk^T+bk (z=1). Exactly 256 jobs
// = one clean round at 1 block/CU. XCD-chunked (256 = 8 x 32), bn
// fastest so the 4 blocks sharing an A panel land on one XCD's L2.
// =====================================================================
__global__ __launch_bounds__(512) void projQK(
    const ushort_t* __restrict__ Qb, const ushort_t* __restrict__ Wqb,
    const float* __restrict__ bq, const float* __restrict__ bk,
    ushort_t* __restrict__ qk, long NQ, long NW)
{
  const int h = blockIdx.x;
  const int s = (h & 7) * 32 + (h >> 3);           // XCD-chunked remap
  const int z = s >> 7, r = s & 127;
  const int bm = r >> 2, bn = r & 3;               // 32 x 4
  gemm256_core<ushort_t>(Qb + (long)z * NQ + (long)bm * 256 * 1024,
                         Wqb + (long)z * NW + (long)bn * 256 * 1024,
                         z ? bk : bq, 1, qk + (long)z * NQ,
                         bm, bn, 1024, 1024, 16, 1.0f);
}

// =====================================================================
// sv8: merged dispatch — 128 vT jobs (independent of q/k; only need
// V/Wv bf16 from cvt) + 256 scores slots (read q/k from projQK).
// Dead upper-triangle scores blocks exit instantly and backfill the
// round; 384 slots ~ 292 real jobs ~ 1.2 rounds instead of 1 + 1.
// Aliasing safe: Sc spans Qb..Qb+2NQ (Q/K staging, dead); V staging at
// Qb+2NQ..+3NQ is untouched by Sc writes.
// =====================================================================
__global__ __launch_bounds__(512) void sv8(
    const ushort_t* __restrict__ qb, const ushort_t* __restrict__ kb,
    const ushort_t* __restrict__ Vb, const ushort_t* __restrict__ Wvb,
    const float* __restrict__ bv,
    ushort_t* __restrict__ Sc, ushort_t* __restrict__ vT,
    const int* __restrict__ j0p)
{
  const int h = blockIdx.x;
  const int s = (h & 7) * 48 + (h >> 3);           // XCD-chunked remap
  if (s < 128) {
    // vT job: vT_b[e,s] = sum_d Wv[e,d] * V_b[s,d] + bv[e]
    const int vb = s >> 5, r = s & 31;
    const int bm = r >> 3, bn = r & 7;             // 4 x 8
    gemm256_core<ushort_t>(Wvb + (long)bm * 256 * 1024,
                           Vb + (long)vb * (2048L * 1024) + (long)bn * 256 * 1024,
                           bv, 2, vT + (long)vb * (1024L * 2048),
                           bm, bn, 2048, 1024, 16, 1.0f);
  } else {
    // scores job: Sc_b = q_b . k_b^T / 32, lower-tri-first remap
    const int job = s - 128;                       // [0,256)
    const int bz = job >> 6;
    const int t = job & 63;
    int bm, bn;
    if (t < 36) {                 // lower triangle (incl diag)
      int r = 0;
      while ((r + 1) * (r + 2) / 2 <= t) ++r;
      bm = r; bn = t - r * (r + 1) / 2;
    } else {                      // strictly upper (usually skipped)
      int u = t - 36, r = 0;
      while (u >= 7 - r) { u -= 7 - r; ++r; }
      bm = r; bn = r + 1 + u;
    }
    if (bn > bm && j0p[bz] <= bm * 256) return;
    const long SD = 2048L * 1024;
    gemm256_core<ushort_t>(qb + (long)bz * SD + (long)bm * 256 * 1024,
                           kb + (long)bz * SD + (long)bn * 256 * 1024,
                           nullptr, 0, Sc + (long)bz * 2048 * 2048,
                           bm, bn, 2048, 1024, 16, 0.03125f);
  }
}

// =====================================================================
// PV: O_b = P_b . vT_b^T with causal K-trim AND split-K makespan fix.
// Gf = K-tiles for row-block bm: (bm+1)*4 if softmax trimmed, else 32.
// Gf > 8 splits across kh; kh=1 -> fp32 partials in scr, combined after.
// =====================================================================
__global__ __launch_bounds__(512) void pv8(
    const ushort_t* __restrict__ P, const ushort_t* __restrict__ vT,
    float* __restrict__ out, float* __restrict__ scr,
    const int* __restrict__ j0p)
{
  const int h = blockIdx.x;
  const int job = (h & 7) * 32 + (h >> 3);         // XCD-chunked remap
  const int bz = job >> 6;
  const int r = job & 63;
  const int bm = r >> 3;
  const int kh = (r >> 2) & 1;
  const int bn = r & 3;

  const int Gf = (j0p[bz] <= bm * 256) ? (bm + 1) * 4 : 32;
  int g0, g1;
  if (Gf > 8) {
    const int half = Gf >> 1;
    g0 = kh ? half : 0;
    g1 = kh ? Gf : half;
  } else {
    if (kh) return;
    g0 = 0; g1 = Gf;
  }

  float* Cc = kh ? (scr + (long)bz * (2048L * 1024))
                 : (out + (long)bz * (2048L * 1024));
  gemm256_core<float>(
      P  + (long)bz * (2048L * 2048) + (long)bm * 256 * 2048 + g0 * 64,
      vT + (long)bz * (1024L * 2048) + (long)bn * 256 * 2048 + g0 * 64,
      nullptr, 0, Cc, bm, bn, 1024, 2048, g1 - g0, 1.0f);
}

// =====================================================================
// Split-K combine: out += scr for rows whose PV block split (Gf > 8).
// =====================================================================
__global__ __launch_bounds__(256) void pv_combine(
    float* __restrict__ out, const float* __restrict__ scr,
    const int* __restrict__ j0p)
{
  const long u = (((long)blockIdx.x * 256) + threadIdx.x) * 8;
  const int bz = (int)(u >> 21);
  const long rem = u & ((1L << 21) - 1);
  const int row = (int)(rem >> 10);
  const int bm = row >> 8;
  const int Gf = (j0p[bz] <= bm * 256) ? (bm + 1) * 4 : 32;
  if (Gf <= 8) return;
  float4* o = reinterpret_cast<float4*>(out + u);
  const float4* s = reinterpret_cast<const float4*>(scr + u);
  float4 o0 = o[0], o1 = o[1], s0 = s[0], s1 = s[1];
  o0.x += s0.x; o0.y += s0.y; o0.z += s0.z; o0.w += s0.w;
  o1.x += s1.x; o1.y += s1.y; o1.z += s1.z; o1.w += s1.w;
  o[0] = o0; o[1] = o1;
}

// =====================================================================
// Row softmax, exact reference ordering; bf16 Sc in, bf16 P out.
// Causal trim at 256 granularity, matched with pv8's K-trim.
// =====================================================================
__global__ __launch_bounds__(256) void softmax_causal(
    const ushort_t* __restrict__ Sc, ushort_t* __restrict__ P,
    const int* __restrict__ mask, const int* __restrict__ j0p, int S)
{
  const int i = blockIdx.x, b = blockIdx.y;
  const ushort_t* row = Sc + ((long)b * S + i) * S;
  ushort_t* prow = P + ((long)b * S + i) * S;
  const int* mrow = mask + (long)b * S;
  const int tid = threadIdx.x;
  const int lane = tid & 63, wave = tid >> 6;
  const int j0 = tid * 8;
  __shared__ float red[4];

  const int blk = i >> 8;
  const int jmax = (j0p[b] <= (blk << 8)) ? ((blk + 1) << 8) : S;
  const bool act = (j0 < jmax);

  float vals[8];
  float mymax = -3.4e38f;
  if (act) {
    bf16x8 sv = *reinterpret_cast<const bf16x8*>(row + j0);
    const int4* mp = reinterpret_cast<const int4*>(mrow + j0);
    int4 m0 = mp[0], m1 = mp[1];
    int mk[8] = {m0.x, m0.y, m0.z, m0.w, m1.x, m1.y, m1.z, m1.w};
    #pragma unroll
    for (int u = 0; u < 8; ++u) {
      const int j = j0 + u;
      float v = (float)sv[u];
      if (mk[u] == 0) v = -1e10f;
      if (j > i) v += -1e10f;
      vals[u] = v;
      mymax = fmaxf(mymax, v);
    }
  }
  #pragma unroll
  for (int off = 32; off; off >>= 1)
    mymax = fmaxf(mymax, __shfl_xor(mymax, off));
  if (lane == 0) red[wave] = mymax;
  __syncthreads();
  const float m = fmaxf(fmaxf(red[0], red[1]), fmaxf(red[2], red[3]));
  __syncthreads();

  float sum = 0.f;
  if (act) {
    #pragma unroll
    for (int u = 0; u < 8; ++u) {
      const float e = __expf(vals[u] - m);
      vals[u] = e;
      sum += e;
    }
  }
  #pragma unroll
  for (int off = 32; off; off >>= 1)
    sum += __shfl_xor(sum, off);
  if (lane == 0) red[wave] = sum;
  __syncthreads();
  const float tot = red[0] + red[1] + red[2] + red[3];
  const float inv = 1.0f / tot;

  if (act) {
    bf16x8 pv;
    #pragma unroll
    for (int u = 0; u < 8; ++u) pv[u] = (__bf16)(vals[u] * inv);
    *reinterpret_cast<bf16x8*>(prow + j0) = pv;
  }
}

extern "C" void kernel_launch(void* const* d_in, const int* in_sizes, int n_in,
                              void* d_out, int out_size, void* d_ws, size_t ws_size,
                              hipStream_t stream)
{
  const int B = 4, S = 2048, D = 1024;
  const float* Q  = (const float*)d_in[0];
  const float* K  = (const float*)d_in[1];
  const float* V  = (const float*)d_in[2];
  const int*   am = (const int*)d_in[3];
  const float* Wq = (const float*)d_in[4];
  const float* bq = (const float*)d_in[5];
  const float* Wk = (const float*)d_in[6];
  const float* bk = (const float*)d_in[7];
  const float* Wv = (const float*)d_in[8];
  const float* bv = (const float*)d_in[9];
  float* out = (float*)d_out;

  const long MS = (long)B * S;       // 8192
  const long NQ = MS * D;            // 8.39M elems = 16 MB bf16
  const long NW = (long)D * D;       // 1.05M elems = 2 MB bf16

  // ws layout (R4-verified); aliases ordering-safe on the sequential
  // stream:
  //  Sc (bf16, 32MB) = Qb..Qb+2NQ  (Q/K staging dead after projQK;
  //                                 V staging at +2NQ untouched)
  //  P  (bf16, 32MB) = qb..kb      (dead after sv8's scores)
  //  scr(fp32, 32MB) = Qb..        (Sc dead after softmax)
  ushort_t* qb = (ushort_t*)d_ws;
  ushort_t* kb = qb + NQ;
  ushort_t* vT = kb + NQ;
  ushort_t* Qb = vT + NQ;            // 3*NQ staging (Qb,Kb,Vb bf16)
  ushort_t* Wqb = Qb + 3 * NQ;
  int* j0 = (int*)(Wqb + 3 * NW);
  ushort_t* Sc = Qb;                 // alias
  ushort_t* P  = qb;                 // alias
  float* scr   = (float*)Qb;         // alias (PV split-K partials)

  // converts (both sizes merged; j0 scan folded in)
  cvt3m<<<dim3((int)(NQ / 2048 + NW / 2048), 3), dim3(256), 0, stream>>>(
      Q, K, V, Wq, Wk, Wv, Qb, Wqb, NQ, NW, am, j0, S, B);

  // q,k projections: exactly 256 jobs = one clean round
  projQK<<<dim3(256), dim3(512), 0, stream>>>(Qb, Wqb, bq, bk, qb, NQ, NW);

  // merged: vT projection (128 jobs) + scores (256 slots, ~164 active)
  sv8<<<dim3(384), dim3(512), 0, stream>>>(qb, kb, Qb + 2 * NQ, Wqb + 2 * NW,
                                           bv, Sc, vT, j0);

  // softmax (mask + causal, reference ordering, 256-granular trim)
  softmax_causal<<<dim3(S, B), dim3(256), 0, stream>>>(Sc, P, am, j0, S);

  // O_b = P_b . vT_b^T, causal K-trim + split-K (max 16 K-tiles/block)
  pv8<<<dim3(256), dim3(512), 0, stream>>>(P, vT, out, scr, j0);
  pv_combine<<<dim3((int)(MS * D / 8 / 256)), dim3(256), 0, stream>>>(out, scr, j0);
}